// Round 5
// baseline (201.246 us; speedup 1.0000x reference)
//
#include <hip/hip_runtime.h>
#include <cstdint>

#define TOK 16384
#define HD 2048
#define NE 64
#define HQ 512
#define KSPLIT 2
#define KSL (HD / KSPLIT)      // 1024 k per block
#define KC 32                  // k chunk
#define NCH (KSL / KC)         // 32 chunks
#define ESCALE 1073741824.0f   // 2^30
#define STB 512                // selthr block size

// ---------------------------------------------------------------------------
// K1: router logits = hid @ rw^T (f32). Block: 256 thr = 4 waves, tile
// 32 tok x 64 exp x 1024 k; thread tile 2 tok x 4 exp. Grid 1024 (512 tg x
// 2 k-slices) = 4 blocks/CU = 16 waves/CU; LDS 26KB (6-block cap).
// 16B-granularity XOR swizzle: A col4^(row&7), B col4^((row>>2)&7) ->
// staging writes AND compute reads both spread over all 8 bank groups.
// ks=0 writes d_out logits; ks=1 writes P1 partials (no atomics anywhere).
// Fused per-block colsum -> csP (deterministic reduce in k_reduce_cs).
// ---------------------------------------------------------------------------
__global__ __launch_bounds__(256, 4) void k_router(const float* __restrict__ hid,
                                                   const float* __restrict__ rw,
                                                   float* __restrict__ logits,
                                                   float* __restrict__ P1,
                                                   float* __restrict__ csP) {
  __shared__ __align__(16) float As[2][32][KC];   // 8 KB
  __shared__ __align__(16) float Bs[2][64][KC];   // 16 KB
  __shared__ float red[2][8][32];                 // 2 KB
  const int tid = threadIdx.x;
  const int lane = tid & 63;
  const int w = tid >> 6;
  const int tm = lane >> 3, tn = lane & 7;
  const int tsub = w >> 1, ehalf = w & 1;
  const int bid = blockIdx.x;
  const int tg = bid >> 1, ks = bid & 1;
  const int t0 = tg * 32;
  const int k0 = ks * KSL;
  // staging indices (swizzled at float4 granularity)
  const int arow = tid >> 3;                               // 0..31
  const int acol4 = tid & 7;                               // 0..7
  const int aoff = ((acol4 ^ (arow & 7)) << 2);
  const int brow = tid >> 2;                               // 0..63
  const int bc0 = (tid & 3) * 2;
  const int bswz = (brow >> 2) & 7;
  const int boff0 = (((bc0 + 0) ^ bswz) << 2);
  const int boff1 = (((bc0 + 1) ^ bswz) << 2);
  const float* hap = hid + (size_t)(t0 + arow) * HD + k0 + acol4 * 4;
  const float* bap = rw + (size_t)brow * HD + k0 + bc0 * 4;
  float4 a4 = *(const float4*)(hap);
  float4 b40 = *(const float4*)(bap);
  float4 b41 = *(const float4*)(bap + 4);
  float acc[2][4];
#pragma unroll
  for (int i = 0; i < 2; ++i)
#pragma unroll
    for (int j = 0; j < 4; ++j) acc[i][j] = 0.f;
  const int rA = tsub * 16 + tm;        // token rows rA, rA+8 ((r&7)==tm)
  const int rB = ehalf * 32 + tn * 4;   // expert rows rB..rB+3 ((r>>2)&7==tn)
  const int cshalf = (tid >> 5) & 1;
  const int csgrp = (tid >> 6) * 2 + cshalf;  // 0..7, 4 rows each
  const int cscol = tid & 31;

  for (int c = 0; c < NCH; ++c) {
    const int cur = c & 1;
    *(float4*)&As[cur][arow][aoff] = a4;
    *(float4*)&Bs[cur][brow][boff0] = b40;
    *(float4*)&Bs[cur][brow][boff1] = b41;
    if (c + 1 < NCH) {
      a4 = *(const float4*)(hap + (c + 1) * KC);
      b40 = *(const float4*)(bap + (c + 1) * KC);
      b41 = *(const float4*)(bap + (c + 1) * KC + 4);
    }
    __syncthreads();
    // flush previous chunk's colsum partial (no atomics)
    if (c > 0 && tid < 32) {
      const int pb = cur ^ 1;
      float v = red[pb][0][tid] + red[pb][1][tid] + red[pb][2][tid] +
                red[pb][3][tid] + red[pb][4][tid] + red[pb][5][tid] +
                red[pb][6][tid] + red[pb][7][tid];
      csP[(size_t)bid * KSL + (c - 1) * KC + tid] = v;
    }
    // this chunk's colsum partial (swizzle-aware reads, 2-way max = free)
    {
      float s = 0.f;
#pragma unroll
      for (int i = 0; i < 4; ++i) {
        const int row = csgrp * 4 + i;
        s += As[cur][row][(((cscol >> 2) ^ (row & 7)) << 2) + (cscol & 3)];
      }
      red[cur][csgrp][cscol] = s;
    }
    // compute: 8 q-iters x (6 conflict-free b128 reads + 32 FMA)
#pragma unroll
    for (int q = 0; q < 8; ++q) {
      const int oa = (q ^ tm) << 2;
      const int ob = (q ^ tn) << 2;
      float4 a0 = *(const float4*)&As[cur][rA][oa];
      float4 a1 = *(const float4*)&As[cur][rA + 8][oa];
      float4 b0 = *(const float4*)&Bs[cur][rB + 0][ob];
      float4 b1 = *(const float4*)&Bs[cur][rB + 1][ob];
      float4 b2 = *(const float4*)&Bs[cur][rB + 2][ob];
      float4 b3 = *(const float4*)&Bs[cur][rB + 3][ob];
      acc[0][0] = fmaf(a0.x, b0.x, acc[0][0]);
      acc[0][0] = fmaf(a0.y, b0.y, acc[0][0]);
      acc[0][0] = fmaf(a0.z, b0.z, acc[0][0]);
      acc[0][0] = fmaf(a0.w, b0.w, acc[0][0]);
      acc[0][1] = fmaf(a0.x, b1.x, acc[0][1]);
      acc[0][1] = fmaf(a0.y, b1.y, acc[0][1]);
      acc[0][1] = fmaf(a0.z, b1.z, acc[0][1]);
      acc[0][1] = fmaf(a0.w, b1.w, acc[0][1]);
      acc[0][2] = fmaf(a0.x, b2.x, acc[0][2]);
      acc[0][2] = fmaf(a0.y, b2.y, acc[0][2]);
      acc[0][2] = fmaf(a0.z, b2.z, acc[0][2]);
      acc[0][2] = fmaf(a0.w, b2.w, acc[0][2]);
      acc[0][3] = fmaf(a0.x, b3.x, acc[0][3]);
      acc[0][3] = fmaf(a0.y, b3.y, acc[0][3]);
      acc[0][3] = fmaf(a0.z, b3.z, acc[0][3]);
      acc[0][3] = fmaf(a0.w, b3.w, acc[0][3]);
      acc[1][0] = fmaf(a1.x, b0.x, acc[1][0]);
      acc[1][0] = fmaf(a1.y, b0.y, acc[1][0]);
      acc[1][0] = fmaf(a1.z, b0.z, acc[1][0]);
      acc[1][0] = fmaf(a1.w, b0.w, acc[1][0]);
      acc[1][1] = fmaf(a1.x, b1.x, acc[1][1]);
      acc[1][1] = fmaf(a1.y, b1.y, acc[1][1]);
      acc[1][1] = fmaf(a1.z, b1.z, acc[1][1]);
      acc[1][1] = fmaf(a1.w, b1.w, acc[1][1]);
      acc[1][2] = fmaf(a1.x, b2.x, acc[1][2]);
      acc[1][2] = fmaf(a1.y, b2.y, acc[1][2]);
      acc[1][2] = fmaf(a1.z, b2.z, acc[1][2]);
      acc[1][2] = fmaf(a1.w, b2.w, acc[1][2]);
      acc[1][3] = fmaf(a1.x, b3.x, acc[1][3]);
      acc[1][3] = fmaf(a1.y, b3.y, acc[1][3]);
      acc[1][3] = fmaf(a1.z, b3.z, acc[1][3]);
      acc[1][3] = fmaf(a1.w, b3.w, acc[1][3]);
    }
  }
  __syncthreads();
  // final colsum flush (chunk NCH-1 lives in red[1])
  if (tid < 32) {
    float v = red[1][0][tid] + red[1][1][tid] + red[1][2][tid] +
              red[1][3][tid] + red[1][4][tid] + red[1][5][tid] +
              red[1][6][tid] + red[1][7][tid];
    csP[(size_t)bid * KSL + (NCH - 1) * KC + tid] = v;
  }
  // output: ks=0 -> logits (d_out), ks=1 -> P1 partials. Coalesced float4.
  float* outp = (ks == 0) ? logits : P1;
  const int tA = t0 + rA;
  *(float4*)&outp[(size_t)tA * NE + rB] =
      make_float4(acc[0][0], acc[0][1], acc[0][2], acc[0][3]);
  *(float4*)&outp[(size_t)(tA + 8) * NE + rB] =
      make_float4(acc[1][0], acc[1][1], acc[1][2], acc[1][3]);
}

// ---------------------------------------------------------------------------
// K1b: colsum[k] = sum over 512 token-groups (fixed order, deterministic).
// ---------------------------------------------------------------------------
__global__ __launch_bounds__(256) void k_reduce_cs(const float* __restrict__ csP,
                                                   float* __restrict__ colsum) {
  __shared__ float rr[4][64];
  const int tid = threadIdx.x;
  const int k = blockIdx.x * 64 + (tid & 63);
  const int ks = k >> 10, ko = k & 1023;
  const int part = tid >> 6;
  float s = 0.f;
  for (int tg = part * 128; tg < part * 128 + 128; ++tg)
    s += csP[(size_t)(tg * 2 + ks) * KSL + ko];
  rr[part][tid & 63] = s;
  __syncthreads();
  if (tid < 64)
    colsum[blockIdx.x * 64 + tid] = rr[0][tid] + rr[1][tid] + rr[2][tid] + rr[3][tid];
}

// ---------------------------------------------------------------------------
// K2a: h = relu(cap_w1 @ mean_h + b1), one block per output row.
// ---------------------------------------------------------------------------
__global__ __launch_bounds__(256) void k_cap1(const float* __restrict__ w1,
                                              const float* __restrict__ b1,
                                              const float* __restrict__ colsum,
                                              float* __restrict__ h) {
  const int row = blockIdx.x;
  const int tid = threadIdx.x;
  const float invB = 1.0f / 16384.0f;
  const float* wr = w1 + (size_t)row * HD;
  float4 a0 = *(const float4*)(wr + tid * 4);
  float4 a1 = *(const float4*)(wr + 1024 + tid * 4);
  float4 c0 = *(const float4*)(colsum + tid * 4);
  float4 c1 = *(const float4*)(colsum + 1024 + tid * 4);
  float s = a0.x * (c0.x * invB) + a0.y * (c0.y * invB) +
            a0.z * (c0.z * invB) + a0.w * (c0.w * invB) +
            a1.x * (c1.x * invB) + a1.y * (c1.y * invB) +
            a1.z * (c1.z * invB) + a1.w * (c1.w * invB);
#pragma unroll
  for (int off = 32; off; off >>= 1) s += __shfl_down(s, off);
  __shared__ float wsum[4];
  if ((tid & 63) == 0) wsum[tid >> 6] = s;
  __syncthreads();
  if (tid == 0) {
    float t = wsum[0] + wsum[1] + wsum[2] + wsum[3] + b1[row];
    h[row] = fmaxf(t, 0.f);
  }
}

// ---------------------------------------------------------------------------
// K2b+c fused: cap_logits = cap_w2 @ h + b2, softmax, clip, capacity.
// One block, 256 thr (4 threads per expert), then wave-0 softmax.
// ---------------------------------------------------------------------------
__global__ __launch_bounds__(256) void k_caphead(const float* __restrict__ w2,
                                                 const float* __restrict__ b2,
                                                 const float* __restrict__ h,
                                                 int* __restrict__ cap) {
  __shared__ float clS[64];
  const int tid = threadIdx.x;
  const int e = tid >> 2, part = tid & 3;
  const float* wr = w2 + (size_t)e * HQ + part * 128;
  const float* hp = h + part * 128;
  float s = 0.f;
#pragma unroll
  for (int i = 0; i < 32; ++i) {
    float4 a = *(const float4*)(wr + i * 4);
    float4 hv = *(const float4*)(hp + i * 4);
    s += a.x * hv.x + a.y * hv.y + a.z * hv.z + a.w * hv.w;
  }
  s += __shfl_down(s, 1);
  s += __shfl_down(s, 2);
  if (part == 0) clS[e] = s + b2[e];
  __syncthreads();
  if (tid < 64) {
    float l = clS[tid];
    float m = l;
#pragma unroll
    for (int off = 1; off < 64; off <<= 1) m = fmaxf(m, __shfl_xor(m, off));
    float ex = expf(l - m);
    float sum = ex;
#pragma unroll
    for (int off = 1; off < 64; off <<= 1) sum += __shfl_xor(sum, off);
    float wgt = ex / sum;
    float cf = 1.25f + (wgt - 0.5f) * 1.0f;
    cf = fminf(fmaxf(cf, 1.0f), 2.0f);
    cap[tid] = (int)floorf(16384.0f * cf / 64.0f);
  }
}

// ---------------------------------------------------------------------------
// K3a: logits += P1 (deterministic 2-way sum, in place on d_out), per-token
// softmax, probsT [e][t], entropy (int64 fixed-point atomic).
// ---------------------------------------------------------------------------
__global__ __launch_bounds__(256) void k_softmax(float* __restrict__ logits,
                                                 const float* __restrict__ P1,
                                                 float* __restrict__ probsT,
                                                 unsigned long long* __restrict__ ent) {
  __shared__ float tpT[64][65];
  __shared__ float sw[4];
  const int tid = threadIdx.x;
  const int lane = tid & 63;
  const int wv = tid >> 6;
  const int t0 = blockIdx.x * 64;
  const int tt = tid >> 2, q = tid & 3;
  float* lr = logits + (size_t)(t0 + tt) * NE + q * 16;
  const float* pr = P1 + (size_t)(t0 + tt) * NE + q * 16;
  float l[16];
#pragma unroll
  for (int i = 0; i < 16; i += 4) {
    float4 v0 = *(const float4*)(lr + i);
    float4 v1 = *(const float4*)(pr + i);
    l[i + 0] = v0.x + v1.x; l[i + 1] = v0.y + v1.y;
    l[i + 2] = v0.z + v1.z; l[i + 3] = v0.w + v1.w;
  }
#pragma unroll
  for (int i = 0; i < 16; i += 4)
    *(float4*)(lr + i) = make_float4(l[i], l[i + 1], l[i + 2], l[i + 3]);
  float m = l[0];
#pragma unroll
  for (int i = 1; i < 16; ++i) m = fmaxf(m, l[i]);
  m = fmaxf(m, __shfl_xor(m, 1));
  m = fmaxf(m, __shfl_xor(m, 2));
  float p[16];
  float s = 0.f;
#pragma unroll
  for (int i = 0; i < 16; ++i) { p[i] = expf(l[i] - m); s += p[i]; }
  s += __shfl_xor(s, 1);
  s += __shfl_xor(s, 2);
  const float inv = 1.0f / s;
  float el = 0.f;
#pragma unroll
  for (int i = 0; i < 16; ++i) {
    float pp = p[i] * inv;
    p[i] = pp;
    el += pp * logf(pp + 1e-8f);
  }
  el += __shfl_xor(el, 1);
  el += __shfl_xor(el, 2);
#pragma unroll
  for (int i = 0; i < 16; ++i) tpT[q * 16 + i][tt] = p[i];
  float ew = (q == 0) ? el : 0.f;
#pragma unroll
  for (int off = 4; off < 64; off <<= 1) ew += __shfl_xor(ew, off);
  if (lane == 0) sw[wv] = ew;
  __syncthreads();
  if (tid == 0) {
    float bt = sw[0] + sw[1] + sw[2] + sw[3];
    atomicAdd(ent, (unsigned long long)(long long)__float2ll_rn(bt * ESCALE));
  }
  const int er = tid >> 6, tl = tid & 63;
#pragma unroll
  for (int pass = 0; pass < 16; ++pass) {
    const int e = pass * 4 + er;
    probsT[(size_t)e * TOK + t0 + tl] = tpT[e][tl];
  }
}

// ---------------------------------------------------------------------------
// K3b: per-expert exact k-th largest prob: 3-pass radix select (11/11/10
// bits, 2048-bin LDS hist, uint4 loads, parallel suffix scan), 512 thr.
// ---------------------------------------------------------------------------
__global__ __launch_bounds__(STB) void k_selthr(const float* __restrict__ probsT,
                                                const int* __restrict__ cap,
                                                unsigned* __restrict__ thrT,
                                                int* __restrict__ cutoff) {
  const int e = blockIdx.x, tid = threadIdx.x;
  const uint4* col4 = (const uint4*)(probsT + (size_t)e * TOK);
  const unsigned* col = (const unsigned*)(probsT + (size_t)e * TOK);
  __shared__ unsigned hist[2048];
  __shared__ int wsfx[STB];
  __shared__ unsigned sh_pref;
  __shared__ int sh_rem;
  __shared__ int sred[8], sgt[8], seq2[8];
  const int k = cap[e];
  unsigned prefix = 0, pmask = 0;
  int rem = k;
#pragma unroll
  for (int pass = 0; pass < 3; ++pass) {
    const int shift = (pass == 0) ? 21 : (pass == 1) ? 10 : 0;
    const int nb = (pass == 2) ? 1024 : 2048;
    const unsigned bmask = nb - 1;
    for (int i = tid; i < nb; i += STB) hist[i] = 0;
    __syncthreads();
    for (int it = 0; it < TOK / (4 * STB); ++it) {
      uint4 v = col4[it * STB + tid];
      if ((v.x & pmask) == prefix) atomicAdd(&hist[(v.x >> shift) & bmask], 1u);
      if ((v.y & pmask) == prefix) atomicAdd(&hist[(v.y >> shift) & bmask], 1u);
      if ((v.z & pmask) == prefix) atomicAdd(&hist[(v.z >> shift) & bmask], 1u);
      if ((v.w & pmask) == prefix) atomicAdd(&hist[(v.w >> shift) & bmask], 1u);
    }
    __syncthreads();
    const int cs = nb / STB;  // 4 or 2 bins per thread
    const int base = tid * cs;
    int s = 0;
    for (int m2 = 0; m2 < cs; ++m2) s += (int)hist[base + m2];
    wsfx[tid] = s;
    __syncthreads();
    for (int off = 1; off < STB; off <<= 1) {
      int v = (tid + off < STB) ? wsfx[tid + off] : 0;
      __syncthreads();
      wsfx[tid] += v;
      __syncthreads();
    }
    int r = (tid < STB - 1) ? wsfx[tid + 1] : 0;
    for (int m2 = cs - 1; m2 >= 0; --m2) {
      int rb = r + (int)hist[base + m2];
      if (rb >= rem && r < rem) {
        sh_pref = prefix | ((unsigned)(base + m2) << shift);
        sh_rem = rem - r;
      }
      r = rb;
    }
    __syncthreads();
    prefix = sh_pref;
    rem = sh_rem;
    pmask |= bmask << shift;
    __syncthreads();
  }
  const unsigned T = prefix;
  int lgt = 0, leq = 0;
  for (int it = 0; it < TOK / (4 * STB); ++it) {
    uint4 v = col4[it * STB + tid];
    lgt += (v.x > T) + (v.y > T) + (v.z > T) + (v.w > T);
    leq += (v.x == T) + (v.y == T) + (v.z == T) + (v.w == T);
  }
#pragma unroll
  for (int off = 32; off; off >>= 1) {
    lgt += __shfl_down(lgt, off);
    leq += __shfl_down(leq, off);
  }
  if ((tid & 63) == 0) { sgt[tid >> 6] = lgt; seq2[tid >> 6] = leq; }
  __syncthreads();
  int c_gt = 0, c_eq = 0;
#pragma unroll
  for (int i = 0; i < 8; ++i) { c_gt += sgt[i]; c_eq += seq2[i]; }
  const int n_allowed = k - c_gt;
  int cut;
  if (n_allowed <= 0) {
    cut = -1;
  } else if (c_eq <= n_allowed) {
    cut = 0x7fffffff;
  } else {
    int lo = 0, hi = TOK - 1;
    while (lo < hi) {
      const int mid = (lo + hi) >> 1;
      int c = 0;
      for (int i = tid; i <= mid; i += STB) c += (col[i] == T);
#pragma unroll
      for (int off = 32; off; off >>= 1) c += __shfl_down(c, off);
      __syncthreads();
      if ((tid & 63) == 0) sred[tid >> 6] = c;
      __syncthreads();
      int cnt = 0;
#pragma unroll
      for (int i = 0; i < 8; ++i) cnt += sred[i];
      if (cnt >= n_allowed) hi = mid; else lo = mid + 1;
    }
    cut = lo;
  }
  if (tid == 0) { thrT[e] = T; cutoff[e] = cut; }
}

// ---------------------------------------------------------------------------
// K3c: per-token selection + weight + entropy finalize.
// ---------------------------------------------------------------------------
__global__ __launch_bounds__(256) void k_final(const float* __restrict__ probsT,
                                               const unsigned* __restrict__ thrT,
                                               const int* __restrict__ cutoff,
                                               const unsigned long long* __restrict__ ent,
                                               float* __restrict__ out_sel,
                                               float* __restrict__ out_w,
                                               float* __restrict__ out_ent) {
  __shared__ float tp[64][65];
  __shared__ unsigned sT[64];
  __shared__ int sC[64];
  const int tid = threadIdx.x;
  const int t0 = blockIdx.x * 64;
  if (tid < 64) { sT[tid] = thrT[tid]; sC[tid] = cutoff[tid]; }
  const int er = tid >> 6, tl2 = tid & 63;
#pragma unroll
  for (int pass = 0; pass < 16; ++pass) {
    const int e = pass * 4 + er;
    tp[e][tl2] = probsT[(size_t)e * TOK + t0 + tl2];
  }
  __syncthreads();
  const int tl = tid >> 2, q = tid & 3;
  const int t_abs = t0 + tl;
  int best = -1;
  float bw = 0.f;
  for (int i = 15; i >= 0; --i) {
    const int e = q * 16 + i;
    const float p = tp[e][tl];
    const unsigned v = __float_as_uint(p);
    const unsigned T = sT[e];
    if (v > T || (v == T && t_abs <= sC[e])) { best = e; bw = p; break; }
  }
#pragma unroll
  for (int off = 1; off <= 2; off <<= 1) {
    const int b2 = __shfl_xor(best, off);
    const float w2 = __shfl_xor(bw, off);
    if (b2 > best) { best = b2; bw = w2; }
  }
  if (q == 0) {
    out_sel[t_abs] = (float)(best >= 0 ? best : 0);
    out_w[t_abs] = (best >= 0 ? bw : 0.0f);
  }
  if (blockIdx.x == 0 && tid == 0)
    out_ent[0] = -((float)(long long)ent[0] * (1.0f / ESCALE)) / 16384.0f;
}

// ---------------------------------------------------------------------------
extern "C" void kernel_launch(void* const* d_in, const int* in_sizes, int n_in,
                              void* d_out, int out_size, void* d_ws, size_t ws_size,
                              hipStream_t stream) {
  (void)in_sizes; (void)n_in; (void)out_size; (void)ws_size;
  const float* hid = (const float*)d_in[0];
  const float* rw  = (const float*)d_in[1];
  const float* w1  = (const float*)d_in[2];
  const float* b1  = (const float*)d_in[3];
  const float* w2  = (const float*)d_in[4];
  const float* b2  = (const float*)d_in[5];
  float* out = (float*)d_out;
  float* logits  = out;
  float* out_sel = out + (size_t)TOK * NE;
  float* out_w   = out_sel + TOK;
  float* out_ent = out_w + TOK;
  char* ws = (char*)d_ws;
  float*              colsum = (float*)(ws + 0);        // 2048 f32
  unsigned long long* ent    = (unsigned long long*)(ws + 8192);
  float*              h      = (float*)(ws + 8448);     // 512 f32
  int*                cap    = (int*)(ws + 10752);
  unsigned*           thr    = (unsigned*)(ws + 11008);
  int*                cut    = (int*)(ws + 11264);
  // region X (4 MiB): csP (written K1, consumed K1b) then probsT (written
  // K3a, consumed K3b/K3c) -- stream-ordered reuse, no overlap.
  float*              csP    = (float*)(ws + 16384);
  float*              probsT = (float*)(ws + 16384);
  float*              P1     = (float*)(ws + 16384 + (size_t)1024 * KSL * 4);  // 4 MiB

  hipMemsetAsync(ent, 0, 8, stream);
  hipLaunchKernelGGL(k_router, dim3(TOK / 32 * KSPLIT), dim3(256), 0, stream,
                     hid, rw, logits, P1, csP);
  hipLaunchKernelGGL(k_reduce_cs, dim3(HD / 64), dim3(256), 0, stream, csP, colsum);
  hipLaunchKernelGGL(k_cap1, dim3(HQ), dim3(256), 0, stream, w1, b1, colsum, h);
  hipLaunchKernelGGL(k_caphead, dim3(1), dim3(256), 0, stream, w2, b2, h, cap);
  hipLaunchKernelGGL(k_softmax, dim3(TOK / 64), dim3(256), 0, stream,
                     logits, P1, probsT, ent);
  hipLaunchKernelGGL(k_selthr, dim3(NE), dim3(STB), 0, stream, probsT, cap, thr, cut);
  hipLaunchKernelGGL(k_final, dim3(TOK / 64), dim3(256), 0, stream,
                     probsT, thr, cut, ent, out_sel, out_w, out_ent);
}